// Round 3
// baseline (2126.313 us; speedup 1.0000x reference)
//
#include <hip/hip_runtime.h>
#include <math.h>

// Problem constants
#define NB 4
#define TT 4096
#define CD 2048
#define NE 64
#define TOPK 6
#define NROWS (NB * TT)                        // 16384
#define OUT_W_OFF ((size_t)NROWS * TOPK)       // 98304
#define OUT_AUX_OFF (2 * (size_t)NROWS * TOPK) // 196608

// Tiling: lane=expert, wave owns 8 rows x full K. 4 waves -> 32 rows/block.
#define THREADS 256
#define WAVES 4
#define RPW 8
#define RPB 32
#define BK 32
#define NCHUNK (CD / BK)   // 64

// LDS slot swizzle: row stride 32 floats (128B), col XOR'd by 4*(row&7)
// (m201 st-style): spreads 64 distinct-row b128 reads across banks.
__device__ __forceinline__ int swz(int row, int col) {
    return row * BK + (col ^ (4 * (row & 7)));
}

extern "C" __global__ __launch_bounds__(THREADS, 2)
void moe_gate_kernel(const float* __restrict__ x, const float* __restrict__ w,
                     float* __restrict__ out, float* __restrict__ gsum,
                     float* __restrict__ gcnt)
{
    __shared__ float ws_[2][NE * BK];    // 2 x 8 KiB
    __shared__ float xs_[2][RPB * BK];   // 2 x 4 KiB
    __shared__ float red_s[WAVES][NE];
    __shared__ float red_c[WAVES][NE];

    const int tid  = threadIdx.x;
    const int wave = tid >> 6;
    const int lane = tid & 63;
    const int row0 = blockIdx.x * RPB;

    // loader mapping: thread t covers tile row t>>3, 16B window 4*(t&7)
    const int lr = tid >> 3;          // 0..31
    const int lc = 4 * (tid & 7);     // 0..28

    const float* wg0 = w + (size_t)lr * CD + lc;          // w rows 0..31
    const float* wg1 = w + (size_t)(32 + lr) * CD + lc;   // w rows 32..63
    const float* xg  = x + (size_t)(row0 + lr) * CD + lc; // x rows row0..row0+31

    const int dw0 = swz(lr, lc);
    const int dw1 = swz(32 + lr, lc);
    const int dx0 = swz(lr, lc);

    float acc[RPW];
    #pragma unroll
    for (int r = 0; r < RPW; ++r) acc[r] = 0.f;

    float4 wA, wB, xA;

    // prologue: stage chunk 0 into buf 0
    wA = *(const float4*)(wg0);
    wB = *(const float4*)(wg1);
    xA = *(const float4*)(xg);
    *(float4*)&ws_[0][dw0] = wA;
    *(float4*)&ws_[0][dw1] = wB;
    *(float4*)&xs_[0][dx0] = xA;
    __syncthreads();

    float4 wr[BK / 4];

#define COMPUTE(BUF)                                                        \
    {                                                                       \
        _Pragma("unroll")                                                   \
        for (int k4 = 0; k4 < BK / 4; ++k4)                                 \
            wr[k4] = *(const float4*)&ws_[BUF][swz(lane, 4 * k4)];          \
        _Pragma("unroll")                                                   \
        for (int r = 0; r < RPW; ++r) {                                     \
            const int rr = wave * RPW + r;                                  \
            _Pragma("unroll")                                               \
            for (int k4 = 0; k4 < BK / 4; ++k4) {                           \
                float4 xv = *(const float4*)&xs_[BUF][swz(rr, 4 * k4)];     \
                acc[r] += xv.x * wr[k4].x + xv.y * wr[k4].y +               \
                          xv.z * wr[k4].z + xv.w * wr[k4].w;                \
            }                                                               \
        }                                                                   \
    }

    for (int c = 0; c < NCHUNK; c += 2) {
        // even body: compute buf0, prefetch+write buf1 for chunk c+1
        {
            const int k0 = (c + 1) * BK;
            if (c + 1 < NCHUNK) {
                wA = *(const float4*)(wg0 + k0);
                wB = *(const float4*)(wg1 + k0);
                xA = *(const float4*)(xg + k0);
            }
            COMPUTE(0)
            if (c + 1 < NCHUNK) {
                *(float4*)&ws_[1][dw0] = wA;
                *(float4*)&ws_[1][dw1] = wB;
                *(float4*)&xs_[1][dx0] = xA;
            }
            __syncthreads();
        }
        // odd body: compute buf1, prefetch+write buf0 for chunk c+2
        {
            const int k0 = (c + 2) * BK;
            if (c + 2 < NCHUNK) {
                wA = *(const float4*)(wg0 + k0);
                wB = *(const float4*)(wg1 + k0);
                xA = *(const float4*)(xg + k0);
            }
            COMPUTE(1)
            if (c + 2 < NCHUNK) {
                *(float4*)&ws_[0][dw0] = wA;
                *(float4*)&ws_[0][dw1] = wB;
                *(float4*)&xs_[0][dx0] = xA;
            }
            __syncthreads();
        }
    }
#undef COMPUTE

    // ---- epilogue: wave owns rows wave*8..+7 fully; lane = expert ----
    float ssum_reg = 0.f;
    float cnt_reg  = 0.f;
    #pragma unroll
    for (int r = 0; r < RPW; ++r) {
        float sc = acc[r];
        float m = sc;
        #pragma unroll
        for (int off = 32; off > 0; off >>= 1) m = fmaxf(m, __shfl_xor(m, off));
        float p = expf(sc - m);
        float tot = p;
        #pragma unroll
        for (int off = 32; off > 0; off >>= 1) tot += __shfl_xor(tot, off);
        float score = p / tot;
        ssum_reg += score;

        float v = score;
        int vi = lane;
        float myidx_f = 0.f, myw = 0.f;
        #pragma unroll
        for (int pk = 0; pk < TOPK; ++pk) {
            float bv = v; int bi = vi;
            #pragma unroll
            for (int off = 32; off > 0; off >>= 1) {
                float ov = __shfl_xor(bv, off);
                int   oi = __shfl_xor(bi, off);
                if (ov > bv || (ov == bv && oi < bi)) { bv = ov; bi = oi; }
            }
            if (lane == pk) { myidx_f = (float)bi; myw = bv; }
            if (lane == bi) { v = -1.0f; cnt_reg += 1.0f; }
        }
        const size_t grow = (size_t)(row0 + wave * RPW + r);
        if (lane < TOPK) {
            out[grow * TOPK + lane]             = myidx_f;
            out[OUT_W_OFF + grow * TOPK + lane] = myw;   // ROUTED_SCALING = 1.0
        }
    }

    // ---- block-level aux partials ----
    red_s[wave][lane] = ssum_reg;
    red_c[wave][lane] = cnt_reg;
    __syncthreads();
    if (tid < NE) {
        float s4 = red_s[0][tid] + red_s[1][tid] + red_s[2][tid] + red_s[3][tid];
        float c4 = red_c[0][tid] + red_c[1][tid] + red_c[2][tid] + red_c[3][tid];
        const int b = blockIdx.x / (TT / RPB);   // 128 blocks per batch
        atomicAdd(&gsum[b * NE + tid], s4);
        atomicAdd(&gcnt[b * NE + tid], c4);
    }
}

extern "C" __global__ void moe_aux_kernel(const float* __restrict__ gsum,
                                          const float* __restrict__ gcnt,
                                          float* __restrict__ out_aux)
{
    const int tid = threadIdx.x;  // 256 = NB*NE
    float v = gcnt[tid] * gsum[tid];
    #pragma unroll
    for (int off = 32; off > 0; off >>= 1) v += __shfl_xor(v, off);
    __shared__ float partial[4];
    if ((tid & 63) == 0) partial[tid >> 6] = v;
    __syncthreads();
    if (tid == 0) {
        float t = partial[0] + partial[1] + partial[2] + partial[3];
        // aux = ALPHA * mean_b( sum_e (cnt/(T*K/E)) * (ssum/T) )
        out_aux[0] = t * (0.001f / (NB * 384.0f * (float)TT));
    }
}

extern "C" void kernel_launch(void* const* d_in, const int* in_sizes, int n_in,
                              void* d_out, int out_size, void* d_ws, size_t ws_size,
                              hipStream_t stream) {
    const float* x = (const float*)d_in[0];
    const float* w = (const float*)d_in[1];
    float* out  = (float*)d_out;
    float* gsum = (float*)d_ws;
    float* gcnt = gsum + NB * NE;
    hipMemsetAsync(d_ws, 0, 2 * NB * NE * sizeof(float), stream);
    moe_gate_kernel<<<NROWS / RPB, THREADS, 0, stream>>>(x, w, out, gsum, gcnt);
    moe_aux_kernel<<<1, 256, 0, stream>>>(gsum, gcnt, out + OUT_AUX_OFF);
}